// Round 18
// baseline (147.776 us; speedup 1.0000x reference)
//
#include <hip/hip_runtime.h>
#include <math.h>

typedef __attribute__((ext_vector_type(4))) float f32x4;
typedef __attribute__((ext_vector_type(4))) int   i32x4;
typedef __attribute__((ext_vector_type(8))) int   i32x8;

#define AS1 __attribute__((address_space(1)))
#define AS3 __attribute__((address_space(3)))

#define N_ROWS 8192
#define DFULL 768
#define KSC (1.4426950408889634f / 0.05f)
#define NEGSH (-28.853900817779268f)   // -20 * log2(e)
#define LN2 0.6931471805599453f
// Schraudolph fast-exp2 (mean-zero bias)
#define EXPA 8388608.0f
#define FEXPC ((NEGSH + 126.9427f) * 8388608.0f)
#define DIAGC (LN2 / 8388608.0f)

__device__ __forceinline__ void gload_lds16(const void* g, void* l) {
  __builtin_amdgcn_global_load_lds((const AS1 void*)g, (AS3 void*)l, 16, 0, 0);
}

// ---------------- kernel 1: per-row prefix norms + fp8 e4m3 convert (row-major) ----------
__global__ __launch_bounds__(192) void mcl_prep(
    const float* __restrict__ e1, const float* __restrict__ e2,
    char* __restrict__ h1, char* __restrict__ h2,
    float* __restrict__ inv1, float* __restrict__ inv2)
{
  const int b = blockIdx.x;
  const int mat = b >> 13, row = b & (N_ROWS - 1);
  const float* src = (mat ? e2 : e1) + (size_t)row * DFULL;
  char* dst = (mat ? h2 : h1) + (size_t)row * DFULL;
  float* invo = mat ? inv2 : inv1;
  const int t = threadIdx.x;
  const int k = t * 4;

  const f32x4 v = *(const f32x4*)(src + k);
  const float s = v[0]*v[0] + v[1]*v[1] + v[2]*v[2] + v[3]*v[3];
  float p0 = (k < 64)  ? s : 0.f;
  float p1 = (k < 128) ? s : 0.f;
  float p2 = (k < 256) ? s : 0.f;
  float p3 = (k < 512) ? s : 0.f;
  float p4 = s;

  const int lo = __builtin_amdgcn_cvt_pk_fp8_f32(v[0], v[1], 0, false);
  const int pk = __builtin_amdgcn_cvt_pk_fp8_f32(v[2], v[3], lo, true);
  *(int*)(dst + k) = pk;

#pragma unroll
  for (int off = 32; off > 0; off >>= 1) {
    p0 += __shfl_down(p0, off, 64);
    p1 += __shfl_down(p1, off, 64);
    p2 += __shfl_down(p2, off, 64);
    p3 += __shfl_down(p3, off, 64);
    p4 += __shfl_down(p4, off, 64);
  }
  __shared__ float red[3][5];
  const int lane = t & 63, w = t >> 6;
  if (lane == 0) { red[w][0]=p0; red[w][1]=p1; red[w][2]=p2; red[w][3]=p3; red[w][4]=p4; }
  __syncthreads();
  if (t == 0) {
#pragma unroll
    for (int q = 0; q < 5; ++q) {
      const float sum = red[0][q] + red[1][q] + red[2][q];
      invo[q * N_ROWS + row] = 1.f / fmaxf(sqrtf(sum), 1e-8f);
    }
  }
}

// ---------------- kernel 2: MX-fp8 GEMM, LDS-broadcast staging, pipelined softmax -------
// Double-buffered LDS (2 x 2 x 16KB): each chunk's 128-row x 128B A/B panels staged ONCE
// per block via global_load_lds (halves L2 traffic). XOR swizzle slot^=(row&7) applied on
// the SOURCE address (linear LDS dest) and on the ds_read addr (r6-proven geometry).
// Chunk CK reads LDS buffer CK&1 (r17 bug: passed chunk number -> OOB smem).
// Swapped operands: acc[n][m] = mfma(bf[n], af[m], .) ->
//   i (softmax row) = wr*64 + m*16 + (lane&15)         [lane-low]
//   j (reduce axis) = wc*64 + n*16 + (lane>>4)*4 + rg  [register + lane-hi]
__global__ __launch_bounds__(256, 2) void mcl_main(
    const char* __restrict__ h1, const char* __restrict__ h2,
    const float* __restrict__ inv1, const float* __restrict__ inv2,
    float* __restrict__ diag, float* __restrict__ partial)
{
  __shared__ __align__(16) char smem[2][2][16384];   // [buf][mat][row*128 + slot*16]
  __shared__ float rowsumW[2][5][128];

  const int tid = threadIdx.x;
  const int lane = tid & 63, wid = tid >> 6;
  const int wr = wid >> 1, wc = wid & 1;
  const int l15 = lane & 15, lh = lane >> 4;
  const int rgd = l15 & 3;
  const int r8 = lane >> 3;                 // staging sub-row 0..7
  const int sor = (lane & 7) ^ r8;          // pre-swizzled source slot

  // XCD-chunked + 8x8-supertile swizzle (bijective: 4096 = 8 * 512)
  const int id = blockIdx.x;
  const int nid = (id & 7) * 512 + (id >> 3);
  const int st = nid >> 6, tt = nid & 63;
  const int bi = ((st >> 3) << 3) + (tt >> 3);
  const int bj = ((st & 7) << 3) + (tt & 7);
  const int rowA0 = bi * 128, rowB0 = bj * 128;
  const bool dgb = (bi == bj) && (wr == wc) && (lh == (l15 >> 2));

  f32x4 acc[4][4];  // [n][m]
#pragma unroll
  for (int n = 0; n < 4; ++n)
#pragma unroll
    for (int m = 0; m < 4; ++m) acc[n][m] = (f32x4)0.f;

#define STAGE(BUF, CK) do {                                                    \
    _Pragma("unroll")                                                          \
    for (int i = 0; i < 4; ++i) {                                              \
      const int lrow = i * 32 + wid * 8 + r8;                                  \
      gload_lds16(h1 + (size_t)(rowA0 + lrow) * DFULL + (CK) * 128 + sor * 16, \
                  &smem[BUF][0][i * 4096 + wid * 1024]);                       \
      gload_lds16(h2 + (size_t)(rowB0 + lrow) * DFULL + (CK) * 128 + sor * 16, \
                  &smem[BUF][1][i * 4096 + wid * 1024]);                       \
    } } while (0)

#define FRAG(DST, BASE, ROWX) do {                                             \
    const int s1_ = (((lh << 1) ^ ((ROWX) & 7)) << 4);                         \
    const i32x4 lo_ = *(const i32x4*)((BASE) + (ROWX) * 128 + s1_);            \
    const i32x4 hi_ = *(const i32x4*)((BASE) + (ROWX) * 128 + (s1_ ^ 16));     \
    DST = __builtin_shufflevector(lo_, hi_, 0, 1, 2, 3, 4, 5, 6, 7); } while (0)

#define LOADF(CUR) do {                                                        \
    const char* bA_ = (const char*)smem[CUR][0];                               \
    const char* bB_ = (const char*)smem[CUR][1];                               \
    _Pragma("unroll")                                                          \
    for (int m = 0; m < 4; ++m) {                                              \
      FRAG(af[m], bA_, wr * 64 + m * 16 + l15);                                \
      FRAG(bf[m], bB_, wc * 64 + m * 16 + l15);                                \
    } } while (0)

#define MFMACL() do {                                                          \
    __builtin_amdgcn_s_setprio(1);                                             \
    _Pragma("unroll")                                                          \
    for (int n = 0; n < 4; ++n)                                                \
      _Pragma("unroll")                                                        \
      for (int m = 0; m < 4; ++m)                                              \
        acc[n][m] = __builtin_amdgcn_mfma_scale_f32_16x16x128_f8f6f4(          \
            bf[n], af[m], acc[n][m], 0, 0, 0, 0x7F, 0, 0x7F);                  \
    __builtin_amdgcn_s_setprio(0);                                             \
  } while (0)

#define SUMEXP(RP, T, S1M) do {                                                \
    const f32x4 ub = (T) * (S1M) + FEXPC;                                      \
    RP += __int_as_float((int)ub[0]) + __int_as_float((int)ub[1]) +            \
          __int_as_float((int)ub[2]) + __int_as_float((int)ub[3]); } while (0)

#define REDUCE_STORE(RP, DCP) do {                                             \
    _Pragma("unroll")                                                          \
    for (int m = 0; m < 4; ++m) {                                              \
      float v_ = (RP)[m];                                                      \
      v_ += __shfl_xor(v_, 16, 64);                                            \
      v_ += __shfl_xor(v_, 32, 64);                                            \
      if (lh == 0) rowsumW[wc][(DCP)][wr * 64 + m * 16 + l15] = v_;            \
    } } while (0)

// scale loads issued BEFORE STAGE: oldest in vmcnt FIFO -> exp waits partial vmcnt only
#define EPIPRE(DCP, S1, S2) do {                                               \
    _Pragma("unroll")                                                          \
    for (int m = 0; m < 4; ++m)                                                \
      S1[m] = inv1[(DCP) * N_ROWS + rowA0 + wr * 64 + m * 16 + l15]            \
              * (KSC * EXPA);                                                  \
    _Pragma("unroll")                                                          \
    for (int n = 0; n < 4; ++n)                                                \
      S2[n] = *(const f32x4*)(inv2 + (DCP) * N_ROWS + rowB0 + wc * 64 +        \
                              n * 16 + (lh << 2));                             \
  } while (0)

#define EPIMAIN(DCP, S1, S2) do {                                              \
    float rp[4] = {0.f, 0.f, 0.f, 0.f};                                        \
    _Pragma("unroll")                                                          \
    for (int n = 0; n < 4; ++n)                                                \
      _Pragma("unroll")                                                        \
      for (int m = 0; m < 4; ++m) {                                            \
        const f32x4 t = acc[n][m] * S2[n];                                     \
        SUMEXP(rp[m], t, S1[m]);                                               \
      }                                                                        \
    REDUCE_STORE(rp, (DCP));                                                   \
    if (dgb) {                                                                 \
      _Pragma("unroll")                                                        \
      for (int m = 0; m < 4; ++m)                                              \
        diag[(DCP) * N_ROWS + rowA0 + wr * 64 + m * 16 + l15] =                \
            acc[m][m][rgd] * S1[m] * S2[m][rgd] * DIAGC;                       \
    } } while (0)

  i32x8 af[4], bf[4];

  STAGE(0, 0);
  __syncthreads();

  // ---- chunk 0 (buf0): masked K<64 pass (dcp0); stage chunk1 into buf1 ----
  {
    float s1a[4]; f32x4 s2a[4];
    EPIPRE(0, s1a, s2a);
    STAGE(1, 1);
    LOADF(0);
    const int msk = (lh < 2) ? 0x7F : 0x00;   // e8m0: 1.0 for k<64 lanes, flush-to-0 else
    float rp0[4] = {0.f, 0.f, 0.f, 0.f};
#pragma unroll
    for (int n = 0; n < 4; ++n) {
#pragma unroll
      for (int m = 0; m < 4; ++m) {
        const f32x4 t = __builtin_amdgcn_mfma_scale_f32_16x16x128_f8f6f4(
            bf[n], af[m], (f32x4)0.f, 0, 0, 0, msk, 0, msk);
        acc[n][m] = __builtin_amdgcn_mfma_scale_f32_16x16x128_f8f6f4(
            bf[n], af[m], acc[n][m], 0, 0, 0, 0x7F, 0, 0x7F);
        const f32x4 ts = t * s2a[n];
        SUMEXP(rp0[m], ts, s1a[m]);
        if (n == m && dgb)
          diag[0 * N_ROWS + rowA0 + wr * 64 + m * 16 + l15] =
              t[rgd] * s1a[m] * s2a[m][rgd] * DIAGC;
      }
    }
    REDUCE_STORE(rp0, 0);
    __syncthreads();
  }
  // ---- chunk 1 (buf1): stage chunk2 into buf0; dcp1 (K=128) exps in shadow ----
  {
    float s1b[4]; f32x4 s2b[4];
    EPIPRE(1, s1b, s2b);
    STAGE(0, 2);
    LOADF(1);
    EPIMAIN(1, s1b, s2b);
    MFMACL();
    __syncthreads();
  }
  // ---- chunk 2 (buf0): stage chunk3 into buf1; dcp2 (K=256) exps ----
  {
    float s1c[4]; f32x4 s2c[4];
    EPIPRE(2, s1c, s2c);
    STAGE(1, 3);
    LOADF(0);
    EPIMAIN(2, s1c, s2c);
    MFMACL();
    __syncthreads();
  }
  // ---- chunk 3 (buf1): stage chunk4 into buf0 ----
  {
    STAGE(0, 4);
    LOADF(1);
    MFMACL();
    __syncthreads();
  }
  // ---- chunk 4 (buf0): stage chunk5 into buf1; dcp3 (K=512) exps ----
  {
    float s1d[4]; f32x4 s2d4[4];
    EPIPRE(3, s1d, s2d4);
    STAGE(1, 5);
    LOADF(0);
    EPIMAIN(3, s1d, s2d4);
    MFMACL();
    __syncthreads();
  }
  // ---- chunk 5 (buf1): final MFMA + dcp4 (K=768) ----
  {
    float s1e[4]; f32x4 s2e[4];
    EPIPRE(4, s1e, s2e);
    LOADF(1);
    MFMACL();
    EPIMAIN(4, s1e, s2e);
  }

#undef EPIMAIN
#undef EPIPRE
#undef REDUCE_STORE
#undef SUMEXP
#undef MFMACL
#undef LOADF
#undef FRAG
#undef STAGE

  __syncthreads();
  for (int x = tid; x < 5 * 128; x += 256) {
    const int d = x >> 7, r = x & 127;
    atomicAdd(&partial[d * N_ROWS + rowA0 + r], rowsumW[0][d][r] + rowsumW[1][d][r]);
  }
}

// ---------------- kernel 3: final reduction ----------------
__global__ __launch_bounds__(256) void mcl_reduce(
    const float* __restrict__ partial, const float* __restrict__ diag,
    float* __restrict__ out)
{
  const int item = blockIdx.x * 256 + threadIdx.x;  // 0..40959
  const int d = item >> 13;
  const int i = item & (N_ROWS - 1);
  const float s = partial[d * N_ROWS + i];
  float term = (20.0f + logf(s) - diag[d * N_ROWS + i]) * (1.0f / 8192.0f);
#pragma unroll
  for (int off = 32; off > 0; off >>= 1) term += __shfl_down(term, off, 64);
  __shared__ float red[4];
  const int lane = threadIdx.x & 63, w = threadIdx.x >> 6;
  if (lane == 0) red[w] = term;
  __syncthreads();
  if (threadIdx.x == 0) atomicAdd(out, red[0] + red[1] + red[2] + red[3]);
}

// ---------------- launcher ----------------
extern "C" void kernel_launch(void* const* d_in, const int* in_sizes, int n_in,
                              void* d_out, int out_size, void* d_ws, size_t ws_size,
                              hipStream_t stream) {
  const float* e1 = (const float*)d_in[0];
  const float* e2 = (const float*)d_in[1];
  char* ws = (char*)d_ws;

  const size_t HBYTES = (size_t)N_ROWS * DFULL;                 // 6,291,456 (fp8)
  const size_t IBYTES = (size_t)5 * N_ROWS * sizeof(float);     //   163,840
  char*  h1      = ws;
  char*  h2      = ws + HBYTES;
  float* inv1    = (float*)(ws + 2 * HBYTES);
  float* inv2    = (float*)(ws + 2 * HBYTES + IBYTES);
  float* diag    = (float*)(ws + 2 * HBYTES + 2 * IBYTES);
  float* partial = (float*)(ws + 2 * HBYTES + 3 * IBYTES);      // 5*8192 floats
  const size_t NEED = 2 * HBYTES + 4 * IBYTES;
  if (ws_size < NEED) return;

  hipMemsetAsync(d_out, 0, sizeof(float) * out_size, stream);
  hipMemsetAsync(partial, 0, IBYTES, stream);
  mcl_prep<<<2 * N_ROWS, 192, 0, stream>>>(e1, e2, h1, h2, inv1, inv2);
  mcl_main<<<4096, 256, 0, stream>>>(h1, h2, inv1, inv2, diag, partial);
  mcl_reduce<<<160, 256, 0, stream>>>(partial, diag, (float*)d_out);
}